// Round 6
// baseline (848.857 us; speedup 1.0000x reference)
//
#include <hip/hip_runtime.h>

#define SEQ 1024
#define BN  512
#define NT  64

typedef float f2 __attribute__((ext_vector_type(2)));

__global__ void zero_out_kernel(float* o) { o[0] = 0.0f; }

#define RPT16(M) M(0) M(1) M(2) M(3) M(4) M(5) M(6) M(7) \
                 M(8) M(9) M(10) M(11) M(12) M(13) M(14) M(15)

// E rows 4k..4k+3 for this lane as NAMED float2 (static access only -> VGPRs)
#define ED(k)                                                          \
  f2 E##k##_0 = { __expf(trans[(4*(k)+0) * NT + lane]),                \
                  __expf(trans[(4*(k)+1) * NT + lane]) };              \
  f2 E##k##_1 = { __expf(trans[(4*(k)+2) * NT + lane]),                \
                  __expf(trans[(4*(k)+3) * NT + lane]) };

// one su float4 chunk -> two v_pk_fma_f32
#define CH(k, SU, A, B) {                                              \
    float4 v = (SU)[k];                                                \
    f2 lo = { v.x, v.y };                                              \
    f2 hi = { v.z, v.w };                                              \
    A = __builtin_elementwise_fma(lo, E##k##_0, A);                    \
    B = __builtin_elementwise_fma(hi, E##k##_1, B);                    \
  }

// full 64-wide matvec for one chain: s_j = sum_i u_i * E[i][j]
#define MV(SU, SOUT) {                                                 \
    f2 A0={0.f,0.f}, A1={0.f,0.f}, A2={0.f,0.f}, A3={0.f,0.f};         \
    f2 B0={0.f,0.f}, B1={0.f,0.f}, B2={0.f,0.f}, B3={0.f,0.f};         \
    CH( 0, SU, A0, B0) CH( 1, SU, A1, B1) CH( 2, SU, A2, B2)           \
    CH( 3, SU, A3, B3) CH( 4, SU, A0, B0) CH( 5, SU, A1, B1)           \
    CH( 6, SU, A2, B2) CH( 7, SU, A3, B3) CH( 8, SU, A0, B0)           \
    CH( 9, SU, A1, B1) CH(10, SU, A2, B2) CH(11, SU, A3, B3)           \
    CH(12, SU, A0, B0) CH(13, SU, A1, B1) CH(14, SU, A2, B2)           \
    CH(15, SU, A3, B3)                                                 \
    f2 S = ((A0 + A1) + (A2 + A3)) + ((B0 + B1) + (B2 + B3));          \
    SOUT = S.x + S.y;                                                  \
  }

extern "C" __global__ __launch_bounds__(64, 1)
void crf_kernel(const float* __restrict__ emis,
                const int*   __restrict__ tags,
                const int*   __restrict__ mask,
                const float* __restrict__ startT,
                const float* __restrict__ endT,
                const float* __restrict__ trans,
                float* __restrict__ out)
{
    const int bA   = 2 * blockIdx.x;      // chain A batch
    const int bB   = bA + 1;              // chain B batch
    const int lane = threadIdx.x;

    // Single wave per block: in-order DS pipe, no barriers anywhere.
    __shared__ __align__(16) float strans[NT * NT];
    __shared__ __align__(16) float suA[NT];
    __shared__ __align__(16) float suB[NT];
    __shared__ int spkA[SEQ];
    __shared__ int spkB[SEQ];

    // ---- one-time staging ----
    {
        const float4* t4 = (const float4*)trans;
        float4* s4 = (float4*)strans;
        #pragma unroll
        for (int k = 0; k < 16; ++k)
            s4[k * NT + lane] = t4[k * NT + lane];
    }
    #pragma unroll
    for (int c = 0; c < SEQ / NT; ++c) {
        int t = c * NT + lane;
        spkA[t] = (tags[t * BN + bA] & 0xFFFF) | (mask[t * BN + bA] << 16);
        spkB[t] = (tags[t * BN + bB] & 0xFFFF) | (mask[t * BN + bB] << 16);
    }
    __threadfence_block();

    // ---- E in registers (shared by both chains): 32 named float2 ----
    RPT16(ED)

    // ---- t = 0 init, both chains ----
    float stv = startT[lane];
    float em0A = emis[(0 * BN + bA) * NT + lane];
    float em0B = emis[(0 * BN + bB) * NT + lane];
    int   tgA = spkA[0] & 0xFFFF;
    int   tgB = spkB[0] & 0xFFFF;
    float al0A = stv + em0A;
    float al0B = stv + em0B;
    float MA = __int_as_float(__builtin_amdgcn_readfirstlane(__float_as_int(al0A)));
    float MB = __int_as_float(__builtin_amdgcn_readfirstlane(__float_as_int(al0B)));
    float uA = __expf(al0A - MA);
    float uB = __expf(al0B - MB);
    float scA = (lane == tgA) ? al0A : 0.0f;
    float scB = (lane == tgB) ? al0B : 0.0f;
    int   ltA = tgA, ltB = tgB;
    int   esA = 0,   esB = 0;
    suA[lane] = uA;
    suB[lane] = uB;

    // ---- depth-4 emissions prefetch per chain (only loop VMEM) ----
    float eA1 = emis[(1 * BN + bA) * NT + lane];
    float eA2 = emis[(2 * BN + bA) * NT + lane];
    float eA3 = emis[(3 * BN + bA) * NT + lane];
    float eA4 = emis[(4 * BN + bA) * NT + lane];
    float eB1 = emis[(1 * BN + bB) * NT + lane];
    float eB2 = emis[(2 * BN + bB) * NT + lane];
    float eB3 = emis[(3 * BN + bB) * NT + lane];
    float eB4 = emis[(4 * BN + bB) * NT + lane];

    const float4* su4A = (const float4*)suA;
    const float4* su4B = (const float4*)suB;

    #pragma unroll 2
    for (int t = 1; t < SEQ; ++t) {
        const float emA_t = eA1;
        const float emB_t = eB1;
        eA1 = eA2; eA2 = eA3; eA3 = eA4;
        eB1 = eB2; eB2 = eB3; eB3 = eB4;
        int tn = t + 4; if (tn > SEQ - 1) tn = SEQ - 1;
        eA4 = emis[(tn * BN + bA) * NT + lane];
        eB4 = emis[(tn * BN + bB) * NT + lane];

        const int pkA = spkA[t], pkB = spkB[t];
        const int tgAt = pkA & 0xFFFF, mkA = pkA >> 16;
        const int tgBt = pkB & 0xFFFF, mkB = pkB >> 16;
        const float TrA = strans[tgA * NT + lane];
        const float TrB = strans[tgB * NT + lane];
        float wA = __expf(emA_t);
        float wB = __expf(emB_t);

        // ---- chain A matvec (B's compute below fills A's read latency) ----
        float sA; MV(su4A, sA)
        float swvA = sA * wA;
        if (mkA) {
            uA = swvA;
            if (lane == tgAt) scA += emA_t + TrA;
            ltA = tgAt;
        }
        if ((t & 1) == 0) {      // deferred exponent-only renorm (every 2 steps)
            int e = __builtin_amdgcn_readfirstlane((__float_as_int(uA) >> 23) & 255);
            uA = ldexpf(uA, 127 - e);
            esA += e - 127;
        }
        suA[lane] = uA;

        // ---- chain B ----
        float sB; MV(su4B, sB)
        float swvB = sB * wB;
        if (mkB) {
            uB = swvB;
            if (lane == tgBt) scB += emB_t + TrB;
            ltB = tgBt;
        }
        if ((t & 1) == 0) {
            int e = __builtin_amdgcn_readfirstlane((__float_as_int(uB) >> 23) & 255);
            uB = ldexpf(uB, 127 - e);
            esB += e - 127;
        }
        suB[lane] = uB;

        tgA = tgAt; tgB = tgBt;
    }

    // ---- epilogue ----
    float ev = __expf(endT[lane]);
    if (lane == ltA) scA += endT[lane];
    if (lane == ltB) scB += endT[lane];
    float vA = uA * ev, vB = uB * ev;
    #pragma unroll
    for (int off = 32; off > 0; off >>= 1) {
        vA  += __shfl_xor(vA,  off, 64);
        vB  += __shfl_xor(vB,  off, 64);
        scA += __shfl_xor(scA, off, 64);
        scB += __shfl_xor(scB, off, 64);
    }
    if (lane == 0) {
        const float LN2 = 0.69314718055994531f;
        float denA = MA + (float)esA * LN2 + __logf(vA);
        float denB = MB + (float)esB * LN2 + __logf(vB);
        atomicAdd(out, (scA - denA) + (scB - denB));
    }
}

extern "C" void kernel_launch(void* const* d_in, const int* in_sizes, int n_in,
                              void* d_out, int out_size, void* d_ws, size_t ws_size,
                              hipStream_t stream)
{
    const float* emis   = (const float*)d_in[0];
    const int*   tags   = (const int*)  d_in[1];
    const int*   mask   = (const int*)  d_in[2];
    const float* startT = (const float*)d_in[3];
    const float* endT   = (const float*)d_in[4];
    const float* trans  = (const float*)d_in[5];
    float* out = (float*)d_out;

    zero_out_kernel<<<1, 1, 0, stream>>>(out);
    crf_kernel<<<dim3(BN / 2), dim3(NT), 0, stream>>>(emis, tags, mask,
                                                      startT, endT, trans, out);
}

// Round 7
// 693.845 us; speedup vs baseline: 1.2234x; 1.2234x over previous
//
#include <hip/hip_runtime.h>

#define SEQ 1024
#define BN  512
#define NT  64
#define NBW 16   // batches per wave in forward kernel

typedef float  v4f __attribute__((ext_vector_type(4)));
typedef __bf16 b8v __attribute__((ext_vector_type(8)));

__global__ void zero_out_kernel(float* o) { o[0] = 0.0f; }

// round-half-up f32->bf16 pack of two values, with exponent-shift bits folded
// in (shbits = (127-e)<<23 implements ldexp(x,127-e) directly in bit domain)
__device__ __forceinline__ unsigned pack_bf2(float lo, float hi, unsigned shbits) {
    unsigned a = __float_as_uint(lo) + shbits + 0x8000u;
    unsigned b = __float_as_uint(hi) + shbits + 0x8000u;
    return (a >> 16) | (b & 0xFFFF0000u);
}

// =====================  forward (denominator) kernel  =====================
// 16 batches per wave. Recursion u_t = w_t (.) (E^T u_{t-1}) runs on MFMA:
//   D[tag_out][batch] = sum_tag_in A[tag_out][tag_in] * B[tag_in][batch]
// A = exp(trans)^T constant in VGPRs; B = u recurrent. Both D (col=lane&15,
// m89-verified) and B (n=lane&15) keep batch==lane&15, so only the tag dim
// crosses lanes -> one small LDS round-trip (2KB) per step.
extern "C" __global__ __launch_bounds__(64, 1)
void crf_fwd(const float* __restrict__ emis,
             const int*   __restrict__ mask_,
             const float* __restrict__ startT,
             const float* __restrict__ endT,
             const float* __restrict__ trans,
             float* __restrict__ out)
{
    const int b0 = blockIdx.x * NBW;
    const int l  = threadIdx.x;
    const int c  = l & 15;      // batch column (MFMA n / D col)
    const int g  = l >> 4;      // lane quad

    // su[batch][tag] bf16, row stride 72*2=144B (pad vs 128 for bank spread)
    __shared__ __align__(16) unsigned short su[NBW][72];

    // ---- A = E^T fragments: A[mt][kh], lane holds A[m=c][k=8g+j] ----
    // value = E[tag_in][tag_out] = exp(trans[tag_in*64 + tag_out])
    b8v A[4][2];
    #pragma unroll
    for (int mt = 0; mt < 4; ++mt) {
        #pragma unroll
        for (int kh = 0; kh < 2; ++kh) {
            uint4 w;
            unsigned* wp = &w.x;
            #pragma unroll
            for (int p = 0; p < 4; ++p) {
                float e0 = __expf(trans[(32*kh + 8*g + 2*p    ) * NT + 16*mt + c]);
                float e1 = __expf(trans[(32*kh + 8*g + 2*p + 1) * NT + 16*mt + c]);
                wp[p] = pack_bf2(e0, e1, 0u);
            }
            A[mt][kh] = __builtin_bit_cast(b8v, w);
        }
    }

    // ---- t=0 init: B_0 = exp(start + em0 - M_c), tag0 normalized to 1 ----
    uint4 Bw[2];
    float M;
    int   es = 0;           // per-batch (col c) exponent ledger
    {
        const float* er0 = emis + (size_t)(b0 + c) * NT;
        float a[16];
        #pragma unroll
        for (int kh = 0; kh < 2; ++kh) {
            float4 s0 = *(const float4*)(startT + 32*kh + 8*g);
            float4 s1 = *(const float4*)(startT + 32*kh + 8*g + 4);
            float4 e0 = *(const float4*)(er0   + 32*kh + 8*g);
            float4 e1 = *(const float4*)(er0   + 32*kh + 8*g + 4);
            a[8*kh+0]=s0.x+e0.x; a[8*kh+1]=s0.y+e0.y;
            a[8*kh+2]=s0.z+e0.z; a[8*kh+3]=s0.w+e0.w;
            a[8*kh+4]=s1.x+e1.x; a[8*kh+5]=s1.y+e1.y;
            a[8*kh+6]=s1.z+e1.z; a[8*kh+7]=s1.w+e1.w;
        }
        M = __shfl(a[0], c, 64);   // alpha0[tag0][c] (lane c has g=0 -> tag 0)
        #pragma unroll
        for (int kh = 0; kh < 2; ++kh) {
            uint4 w;
            unsigned* wp = &w.x;
            #pragma unroll
            for (int p = 0; p < 4; ++p)
                wp[p] = pack_bf2(__expf(a[8*kh+2*p] - M),
                                 __expf(a[8*kh+2*p+1] - M), 0u);
            Bw[kh] = w;
        }
    }

    // ---- depth-3 prefetch: em (B-layout coalesced float4s) + mask ----
    float4 emP[3][4];
    int    mkP[3];
    #pragma unroll
    for (int s = 0; s < 3; ++s) {
        int tl = s + 1;
        const float4* ep = (const float4*)(emis + ((size_t)tl*BN + b0 + c)*NT);
        emP[s][0] = ep[2*g];   emP[s][1] = ep[2*g+1];
        emP[s][2] = ep[2*g+8]; emP[s][3] = ep[2*g+9];
        mkP[s] = mask_[tl*BN + b0 + c];
    }

    const v4f z4 = {0.f, 0.f, 0.f, 0.f};

    #pragma unroll 3
    for (int t = 1; t < SEQ; ++t) {
        const int s = (t - 1) % 3;     // constant per unrolled copy

        // s_t = E^T u_{t-1} on the matrix pipe
        b8v vb0 = __builtin_bit_cast(b8v, Bw[0]);
        b8v vb1 = __builtin_bit_cast(b8v, Bw[1]);
        v4f D[4];
        #pragma unroll
        for (int mt = 0; mt < 4; ++mt) {
            D[mt] = __builtin_amdgcn_mfma_f32_16x16x32_bf16(A[mt][0], vb0, z4,    0,0,0);
            D[mt] = __builtin_amdgcn_mfma_f32_16x16x32_bf16(A[mt][1], vb1, D[mt], 0,0,0);
        }

        // renorm ref = s_t[tag0][c] (lane c, D[0] reg 0); bit-domain ldexp
        float ref = __shfl(D[0][0], c, 64);
        int   e   = (__float_as_int(ref) >> 23) & 255;
        unsigned shb = (unsigned)(127 - e) << 23;
        const int mk = mkP[s];
        es += mk ? (e - 127) : 0;

        // write s_t (renormed bf16) into su[batch][tag]; lane owns tags 16mt+4g..+3
        #pragma unroll
        for (int mt = 0; mt < 4; ++mt) {
            *(unsigned*)&su[c][16*mt + 4*g    ] = pack_bf2(D[mt][0], D[mt][1], shb);
            *(unsigned*)&su[c][16*mt + 4*g + 2] = pack_bf2(D[mt][2], D[mt][3], shb);
        }

        // read back in B-operand layout (in-order DS => all writes precede)
        const char* rowp = (const char*)&su[c][0];
        uint4 r0 = *(const uint4*)(rowp + 16*g);        // tags 8g..8g+7
        uint4 r1 = *(const uint4*)(rowp + 64 + 16*g);   // tags 32+8g..+7

        // u_t = mk ? exp(em_t) (.) s_t : u_{t-1}
        #pragma unroll
        for (int kh = 0; kh < 2; ++kh) {
            float4 ea = emP[s][2*kh], eb = emP[s][2*kh+1];
            float f0=ea.x, f1=ea.y, f2=ea.z, f3=ea.w;
            float f4=eb.x, f5=eb.y, f6=eb.z, f7=eb.w;
            unsigned rw0 = kh ? r1.x : r0.x;
            unsigned rw1 = kh ? r1.y : r0.y;
            unsigned rw2 = kh ? r1.z : r0.z;
            unsigned rw3 = kh ? r1.w : r0.w;
            unsigned c0 = pack_bf2(__uint_as_float(rw0 << 16)         * __expf(f0),
                                   __uint_as_float(rw0 & 0xFFFF0000u) * __expf(f1), 0u);
            unsigned c1 = pack_bf2(__uint_as_float(rw1 << 16)         * __expf(f2),
                                   __uint_as_float(rw1 & 0xFFFF0000u) * __expf(f3), 0u);
            unsigned c2 = pack_bf2(__uint_as_float(rw2 << 16)         * __expf(f4),
                                   __uint_as_float(rw2 & 0xFFFF0000u) * __expf(f5), 0u);
            unsigned c3 = pack_bf2(__uint_as_float(rw3 << 16)         * __expf(f6),
                                   __uint_as_float(rw3 & 0xFFFF0000u) * __expf(f7), 0u);
            unsigned* bp = kh ? &Bw[1].x : &Bw[0].x;
            bp[0] = mk ? c0 : bp[0];
            bp[1] = mk ? c1 : bp[1];
            bp[2] = mk ? c2 : bp[2];
            bp[3] = mk ? c3 : bp[3];
        }

        // late refill of slot s with t+3 (stays ~3 iters / ~1200cy in flight)
        int tl = t + 3; if (tl > SEQ - 1) tl = SEQ - 1;
        const float4* ep = (const float4*)(emis + ((size_t)tl*BN + b0 + c)*NT);
        emP[s][0] = ep[2*g];   emP[s][1] = ep[2*g+1];
        emP[s][2] = ep[2*g+8]; emP[s][3] = ep[2*g+9];
        mkP[s] = mask_[tl*BN + b0 + c];
    }

    // ---- epilogue: den_c = M_c + es*ln2 + log(sum_tag u * exp(end)) ----
    float S = 0.f;
    #pragma unroll
    for (int kh = 0; kh < 2; ++kh) {
        float4 n0 = *(const float4*)(endT + 32*kh + 8*g);
        float4 n1 = *(const float4*)(endT + 32*kh + 8*g + 4);
        float e0=n0.x, e1=n0.y, e2=n0.z, e3=n0.w;
        float e4=n1.x, e5=n1.y, e6=n1.z, e7=n1.w;
        unsigned w0 = kh ? Bw[1].x : Bw[0].x;
        unsigned w1 = kh ? Bw[1].y : Bw[0].y;
        unsigned w2 = kh ? Bw[1].z : Bw[0].z;
        unsigned w3 = kh ? Bw[1].w : Bw[0].w;
        S += __uint_as_float(w0 << 16)*__expf(e0) + __uint_as_float(w0 & 0xFFFF0000u)*__expf(e1);
        S += __uint_as_float(w1 << 16)*__expf(e2) + __uint_as_float(w1 & 0xFFFF0000u)*__expf(e3);
        S += __uint_as_float(w2 << 16)*__expf(e4) + __uint_as_float(w2 & 0xFFFF0000u)*__expf(e5);
        S += __uint_as_float(w3 << 16)*__expf(e6) + __uint_as_float(w3 & 0xFFFF0000u)*__expf(e7);
    }
    S += __shfl_xor(S, 16, 64);
    S += __shfl_xor(S, 32, 64);
    float den = M + (float)es * 0.69314718055994531f + __logf(S);
    float v = (l < 16) ? -den : 0.f;
    #pragma unroll
    for (int off = 1; off < 64; off <<= 1) v += __shfl_xor(v, off, 64);
    if (l == 0) atomicAdd(out, v);
}

// =====================  numerator kernel (no recursion)  =====================
extern "C" __global__ __launch_bounds__(64, 1)
void crf_num(const float* __restrict__ emis,
             const int*   __restrict__ tags,
             const int*   __restrict__ mask_,
             const float* __restrict__ startT,
             const float* __restrict__ endT,
             const float* __restrict__ trans,
             float* __restrict__ out)
{
    const int b = blockIdx.x;
    const int l = threadIdx.x;
    float sc = 0.f;
    int   msum = 0;
    #pragma unroll 4
    for (int i = 0; i < SEQ / 64; ++i) {
        int t  = i * 64 + l;
        int tg = tags[t * BN + b];
        if (t >= 1) {
            int tp = tags[(t - 1) * BN + b];
            int mk = mask_[t * BN + b];
            if (mk) sc += trans[tp * NT + tg] + emis[((size_t)t * BN + b) * NT + tg];
            msum += mk;
        } else {
            sc += startT[tg] + emis[(size_t)b * NT + tg];
            msum += mask_[b];
        }
    }
    #pragma unroll
    for (int off = 32; off > 0; off >>= 1) {
        sc   += __shfl_xor(sc, off, 64);
        msum += __shfl_xor(msum, off, 64);
    }
    if (l == 0) {
        int last_t = msum - 1;
        int lt = tags[last_t * BN + b];
        sc += endT[lt];
        atomicAdd(out, sc);
    }
}

extern "C" void kernel_launch(void* const* d_in, const int* in_sizes, int n_in,
                              void* d_out, int out_size, void* d_ws, size_t ws_size,
                              hipStream_t stream)
{
    const float* emis   = (const float*)d_in[0];
    const int*   tags   = (const int*)  d_in[1];
    const int*   mask   = (const int*)  d_in[2];
    const float* startT = (const float*)d_in[3];
    const float* endT   = (const float*)d_in[4];
    const float* trans  = (const float*)d_in[5];
    float* out = (float*)d_out;

    zero_out_kernel<<<1, 1, 0, stream>>>(out);
    crf_num<<<dim3(BN), dim3(64), 0, stream>>>(emis, tags, mask, startT, endT, trans, out);
    crf_fwd<<<dim3(BN / NBW), dim3(64), 0, stream>>>(emis, mask, startT, endT, trans, out);
}